// Round 7
// baseline (387.769 us; speedup 1.0000x reference)
//
#include <hip/hip_runtime.h>
#include <math.h>

#define NN 10000
#define BB 4
#define EE 160000
#define CC 64
#define CE 16

// ---- workspace layout (bytes), total ~76 MB ----
static constexpr size_t OFF_XPA    = 0;           // float[NN*256]  xp transposed [n][c][b]
static constexpr size_t OFF_XPB    = 10240000;    // float[NN*256]  interlayer act (transposed)
static constexpr size_t OFF_AGG    = 20480000;    // float[NN*256]  aggr transposed [n][c][b]
static constexpr size_t OFF_SA     = 30720000;    // float[NN*BB]
static constexpr size_t OFF_SB     = 30880000;    // float[NN*BB]
static constexpr size_t OFF_VECS   = 31040000;    // float[288]
static constexpr size_t OFF_COUNTS = 31041280;    // int[NN]
static constexpr size_t OFF_CURSOR = 31081280;    // int[NN]
static constexpr size_t OFF_OFFS   = 31121280;    // int[NN+1] (+pad)
static constexpr size_t OFF_RECS   = 31161344;    // int2[EE]
static constexpr size_t OFF_ATT    = 32441344;    // float4[EE]  (2.56 MB)
static constexpr size_t OFF_GATE   = 35001344;    // float[EE*CC] (40.96 MB)

__device__ __forceinline__ float sigmoidf_(float x) {
    return 1.0f / (1.0f + __expf(-x));
}

// histogram of dst + (block 0) fold q@aw_q, k@aw_k, w_e@aw_e for both layers
__global__ void hist_vecs_kernel(const int* __restrict__ ei, int* __restrict__ counts,
                                 const float* __restrict__ q1, const float* __restrict__ k1,
                                 const float* __restrict__ aw1, const float* __restrict__ we1,
                                 const float* __restrict__ q2, const float* __restrict__ k2,
                                 const float* __restrict__ aw2, const float* __restrict__ we2,
                                 float* __restrict__ vecs) {
    int e = blockIdx.x * blockDim.x + threadIdx.x;
    if (e < EE) atomicAdd(&counts[ei[EE + e]], 1);
    if (blockIdx.x == 0) {
        int t = threadIdx.x;
        if (t < 64) {
            float a = 0.f, b = 0.f, c = 0.f, d = 0.f;
            for (int j = 0; j < 64; ++j) {
                a = fmaf(q1[t * 64 + j], aw1[j], a);
                b = fmaf(k1[t * 64 + j], aw1[64 + j], b);
                c = fmaf(q2[t * 64 + j], aw2[j], c);
                d = fmaf(k2[t * 64 + j], aw2[64 + j], d);
            }
            vecs[t] = a; vecs[64 + t] = b; vecs[144 + t] = c; vecs[208 + t] = d;
        }
        if (t < 16) {
            float a = 0.f, b = 0.f;
            for (int j = 0; j < 64; ++j) {
                a = fmaf(we1[t * 64 + j], aw1[128 + j], a);
                b = fmaf(we2[t * 64 + j], aw2[128 + j], b);
            }
            vecs[128 + t] = a; vecs[272 + t] = b;
        }
    }
}

// single-block exclusive scan via wave shuffles
__global__ void scan_kernel(const int* __restrict__ counts, int* __restrict__ offs, int n) {
    __shared__ int wsum[16];
    __shared__ int carry_sh;
    int t = threadIdx.x;
    int lane = t & 63, wid = t >> 6;
    if (t == 0) carry_sh = 0;
    __syncthreads();
    for (int base = 0; base < n; base += 1024) {
        int i = base + t;
        int v = (i < n) ? counts[i] : 0;
        int x = v;
        #pragma unroll
        for (int d = 1; d < 64; d <<= 1) {
            int y = __shfl_up(x, d, 64);
            if (lane >= d) x += y;
        }
        if (lane == 63) wsum[wid] = x;
        __syncthreads();
        if (wid == 0 && lane < 16) {
            int s = wsum[lane];
            int y2 = s;
            #pragma unroll
            for (int d = 1; d < 16; d <<= 1) {
                int z = __shfl_up(y2, d, 16);
                if (lane >= d) y2 += z;
            }
            wsum[lane] = y2;  // inclusive
        }
        __syncthreads();
        int waveExcl = (wid == 0) ? 0 : wsum[wid - 1];
        int carry = carry_sh;
        if (i < n) offs[i] = carry + waveExcl + x - v;
        int total = wsum[15];
        __syncthreads();
        if (t == 0) carry_sh = carry + total;
        __syncthreads();
    }
    if (threadIdx.x == 0) offs[n] = carry_sh;
}

__global__ void scatter_kernel(const int* __restrict__ ei, const int* __restrict__ offs,
                               int* __restrict__ cursor, int2* __restrict__ recs) {
    int e = blockIdx.x * blockDim.x + threadIdx.x;
    if (e >= EE) return;
    int s = ei[e], d = ei[EE + e];
    int p = atomicAdd(&cursor[d], 1);
    recs[offs[d] + p] = make_int2(s, e);
}

// xp_t = transpose(x @ w_n) ; sa = xp@qa ; sb = xp@ka. One wave per node.
template <bool IN_T>
__global__ __launch_bounds__(256) void node_prep_kernel(
    const float* __restrict__ x,
    const float* __restrict__ w_n, // [CC,CC]
    const float* __restrict__ qa,  // [64]
    const float* __restrict__ ka,  // [64]
    float* __restrict__ xp_t,      // [NN][CC][BB]
    float* __restrict__ sa,        // [NN,BB]
    float* __restrict__ sb) {
    __shared__ float w_sh[64 * 64];     // 16 KB
    __shared__ float x_sh[4 * BB * CC]; // 4 KB
    int t = threadIdx.x;
    for (int i = t; i < 64 * 64; i += 256) w_sh[i] = w_n[i];
    int node0 = blockIdx.x * 4;
    const float4* xg = (const float4*)(x + (size_t)node0 * BB * CC);
    ((float4*)x_sh)[t] = xg[t];
    __syncthreads();
    int wave = t >> 6, lane = t & 63;
    int node = node0 + wave;
    const float* xrow = x_sh + wave * BB * CC;
    float acc0 = 0.f, acc1 = 0.f, acc2 = 0.f, acc3 = 0.f;
    #pragma unroll 8
    for (int ci = 0; ci < 64; ++ci) {
        float w = w_sh[ci * 64 + lane];
        float x0 = IN_T ? xrow[ci * 4 + 0] : xrow[ci];
        float x1 = IN_T ? xrow[ci * 4 + 1] : xrow[64 + ci];
        float x2 = IN_T ? xrow[ci * 4 + 2] : xrow[128 + ci];
        float x3 = IN_T ? xrow[ci * 4 + 3] : xrow[192 + ci];
        acc0 = fmaf(x0, w, acc0);
        acc1 = fmaf(x1, w, acc1);
        acc2 = fmaf(x2, w, acc2);
        acc3 = fmaf(x3, w, acc3);
    }
    float4 st; st.x = acc0; st.y = acc1; st.z = acc2; st.w = acc3;
    *(float4*)(xp_t + (size_t)node * 256 + lane * 4) = st;
    float qv = qa[lane], kv = ka[lane];
    float ra0 = acc0 * qv, ra1 = acc1 * qv, ra2 = acc2 * qv, ra3 = acc3 * qv;
    float rb0 = acc0 * kv, rb1 = acc1 * kv, rb2 = acc2 * kv, rb3 = acc3 * kv;
    #pragma unroll
    for (int off = 32; off >= 1; off >>= 1) {
        ra0 += __shfl_xor(ra0, off, 64); ra1 += __shfl_xor(ra1, off, 64);
        ra2 += __shfl_xor(ra2, off, 64); ra3 += __shfl_xor(ra3, off, 64);
        rb0 += __shfl_xor(rb0, off, 64); rb1 += __shfl_xor(rb1, off, 64);
        rb2 += __shfl_xor(rb2, off, 64); rb3 += __shfl_xor(rb3, off, 64);
    }
    if (lane == 0) {
        sa[node * BB + 0] = ra0; sa[node * BB + 1] = ra1;
        sa[node * BB + 2] = ra2; sa[node * BB + 3] = ra3;
        sb[node * BB + 0] = rb0; sb[node * BB + 1] = rb1;
        sb[node * BB + 2] = rb2; sb[node * BB + 3] = rb3;
    }
}

// Producer: one WAVE per edge (no serial loop).
//   gate[e][c] = sigmoid(attr[e]·w_e[:,c])   (lane = c, coalesced 256B store)
//   att[e]     = sigmoid(sa[src]+sb[dst]+attr[e]·weav+ab)  (lane 0)
__global__ __launch_bounds__(256) void edge_gate_att_kernel(
    const int* __restrict__ ei, const float* __restrict__ attr,
    const float* __restrict__ sa, const float* __restrict__ sb,
    const float* __restrict__ w_e,   // [CE,CC]
    const float* __restrict__ weav,  // [16]
    const float* __restrict__ ab,    // [1]
    float4* __restrict__ att, float* __restrict__ gate) {
    int t = threadIdx.x;
    int wid = t >> 6, lane = t & 63;
    int e = blockIdx.x * 4 + wid;

    float wec[CE];
    #pragma unroll
    for (int j = 0; j < CE; ++j) wec[j] = w_e[j * CC + lane];

    const float4* ap = (const float4*)(attr + (size_t)e * CE);
    float4 a0 = ap[0], a1 = ap[1], a2 = ap[2], a3 = ap[3];
    float g = 0.f, se = ab[0];
    g = fmaf(a0.x, wec[0], g);  se = fmaf(a0.x, weav[0], se);
    g = fmaf(a0.y, wec[1], g);  se = fmaf(a0.y, weav[1], se);
    g = fmaf(a0.z, wec[2], g);  se = fmaf(a0.z, weav[2], se);
    g = fmaf(a0.w, wec[3], g);  se = fmaf(a0.w, weav[3], se);
    g = fmaf(a1.x, wec[4], g);  se = fmaf(a1.x, weav[4], se);
    g = fmaf(a1.y, wec[5], g);  se = fmaf(a1.y, weav[5], se);
    g = fmaf(a1.z, wec[6], g);  se = fmaf(a1.z, weav[6], se);
    g = fmaf(a1.w, wec[7], g);  se = fmaf(a1.w, weav[7], se);
    g = fmaf(a2.x, wec[8], g);  se = fmaf(a2.x, weav[8], se);
    g = fmaf(a2.y, wec[9], g);  se = fmaf(a2.y, weav[9], se);
    g = fmaf(a2.z, wec[10], g); se = fmaf(a2.z, weav[10], se);
    g = fmaf(a2.w, wec[11], g); se = fmaf(a2.w, weav[11], se);
    g = fmaf(a3.x, wec[12], g); se = fmaf(a3.x, weav[12], se);
    g = fmaf(a3.y, wec[13], g); se = fmaf(a3.y, weav[13], se);
    g = fmaf(a3.z, wec[14], g); se = fmaf(a3.z, weav[14], se);
    g = fmaf(a3.w, wec[15], g); se = fmaf(a3.w, weav[15], se);
    gate[(size_t)e * CC + lane] = sigmoidf_(g);

    if (lane == 0) {
        int s = ei[e], d = ei[EE + e];
        float4 sas = *(const float4*)(sa + (size_t)s * BB);
        float4 sbn = *(const float4*)(sb + (size_t)d * BB);
        float4 r;
        r.x = sigmoidf_(sas.x + sbn.x + se);
        r.y = sigmoidf_(sas.y + sbn.y + se);
        r.z = sigmoidf_(sas.z + sbn.z + se);
        r.w = sigmoidf_(sas.w + sbn.w + se);
        att[e] = r;
    }
}

// Segment-max: block = 1 node, 4 waves stripe the edge list (stride 4),
// unroll x2 -> ~16 edge-loads in flight per node. Pure loads + max.
__global__ __launch_bounds__(256) void aggr_kernel(
    const float4* __restrict__ xp_t,   // [NN][CC] float4 (b packed)
    const int2* __restrict__ recs,     // [EE] {src, e}
    const int* __restrict__ offs,      // [NN+1]
    const float4* __restrict__ att,    // [EE]
    const float* __restrict__ gate,    // [EE][CC]
    float4* __restrict__ aggr_t) {     // [NN][CC] float4
    __shared__ float4 red[4][64];      // 4 KB
    int t = threadIdx.x;
    int wid = t >> 6, lane = t & 63;
    int node = blockIdx.x;

    int o0 = offs[node], o1 = offs[node + 1];
    float m0 = -INFINITY, m1 = -INFINITY, m2 = -INFINITY, m3 = -INFINITY;

    int i = o0 + wid;
    for (; i + 4 < o1; i += 8) {
        int2 rA = recs[i], rB = recs[i + 4];
        float4 xA = xp_t[(size_t)rA.x * 64 + lane];
        float4 xB = xp_t[(size_t)rB.x * 64 + lane];
        float gA = gate[(size_t)rA.y * CC + lane];
        float gB = gate[(size_t)rB.y * CC + lane];
        float4 AA = att[rA.y], AB = att[rB.y];
        m0 = fmaxf(m0, AA.x * xA.x * gA); m1 = fmaxf(m1, AA.y * xA.y * gA);
        m2 = fmaxf(m2, AA.z * xA.z * gA); m3 = fmaxf(m3, AA.w * xA.w * gA);
        m0 = fmaxf(m0, AB.x * xB.x * gB); m1 = fmaxf(m1, AB.y * xB.y * gB);
        m2 = fmaxf(m2, AB.z * xB.z * gB); m3 = fmaxf(m3, AB.w * xB.w * gB);
    }
    for (; i < o1; i += 4) {
        int2 r = recs[i];
        float4 xv = xp_t[(size_t)r.x * 64 + lane];
        float g = gate[(size_t)r.y * CC + lane];
        float4 at = att[r.y];
        m0 = fmaxf(m0, at.x * xv.x * g); m1 = fmaxf(m1, at.y * xv.y * g);
        m2 = fmaxf(m2, at.z * xv.z * g); m3 = fmaxf(m3, at.w * xv.w * g);
    }
    float4 mv; mv.x = m0; mv.y = m1; mv.z = m2; mv.w = m3;
    red[wid][lane] = mv;
    __syncthreads();
    if (wid == 0) {
        float4 a = red[0][lane], b = red[1][lane], c = red[2][lane], d = red[3][lane];
        m0 = fmaxf(fmaxf(a.x, b.x), fmaxf(c.x, d.x));
        m1 = fmaxf(fmaxf(a.y, b.y), fmaxf(c.y, d.y));
        m2 = fmaxf(fmaxf(a.z, b.z), fmaxf(c.z, d.z));
        m3 = fmaxf(fmaxf(a.w, b.w), fmaxf(c.w, d.w));
        m0 = (m0 == -INFINITY) ? 0.f : m0;
        m1 = (m1 == -INFINITY) ? 0.f : m1;
        m2 = (m2 == -INFINITY) ? 0.f : m2;
        m3 = (m3 == -INFINITY) ? 0.f : m3;
        float4 st; st.x = m0; st.y = m1; st.z = m2; st.w = m3;
        aggr_t[(size_t)node * 64 + lane] = st;
    }
}

// Epilogue GEMM: out = leaky(xp + concat([xp,aggr])@ow + ob).
template <bool WRITE_T>
__global__ __launch_bounds__(256) void out_kernel(
    const float* __restrict__ xp_t,    // [NN][CC][BB]
    const float* __restrict__ aggr_t,  // [NN][CC][BB]
    const float* __restrict__ ow,      // [2*CC,CC]
    const float* __restrict__ ob,      // [CC]
    float* __restrict__ out) {
    __shared__ float xs[4][BB * CC];
    __shared__ float as_[4][BB * CC];
    int t = threadIdx.x;
    int wave = t >> 6, lane = t & 63;
    int node = blockIdx.x * 4 + wave;

    float4 xv = *(const float4*)(xp_t + (size_t)node * 256 + lane * 4);
    float4 av = *(const float4*)(aggr_t + (size_t)node * 256 + lane * 4);
    xs[wave][0 * 64 + lane] = xv.x; xs[wave][1 * 64 + lane] = xv.y;
    xs[wave][2 * 64 + lane] = xv.z; xs[wave][3 * 64 + lane] = xv.w;
    as_[wave][0 * 64 + lane] = av.x; as_[wave][1 * 64 + lane] = av.y;
    as_[wave][2 * 64 + lane] = av.z; as_[wave][3 * 64 + lane] = av.w;
    __syncthreads();

    const float* xr = xs[wave];
    const float* ar = as_[wave];
    float o0f = 0.f, o1f = 0.f, o2f = 0.f, o3f = 0.f;
    #pragma unroll 4
    for (int ci = 0; ci < 64; ++ci) {
        float wa = ow[ci * 64 + lane];
        float wb = ow[(64 + ci) * 64 + lane];
        o0f = fmaf(xr[ci], wa, o0f);
        o1f = fmaf(xr[64 + ci], wa, o1f);
        o2f = fmaf(xr[128 + ci], wa, o2f);
        o3f = fmaf(xr[192 + ci], wa, o3f);
        o0f = fmaf(ar[ci], wb, o0f);
        o1f = fmaf(ar[64 + ci], wb, o1f);
        o2f = fmaf(ar[128 + ci], wb, o2f);
        o3f = fmaf(ar[192 + ci], wb, o3f);
    }
    float obv = ob[lane];
    float r0 = xv.x + o0f + obv;
    float r1 = xv.y + o1f + obv;
    float r2 = xv.z + o2f + obv;
    float r3 = xv.w + o3f + obv;
    r0 = (r0 > 0.f) ? r0 : 0.01f * r0;
    r1 = (r1 > 0.f) ? r1 : 0.01f * r1;
    r2 = (r2 > 0.f) ? r2 : 0.01f * r2;
    r3 = (r3 > 0.f) ? r3 : 0.01f * r3;
    if (WRITE_T) {
        float4 st; st.x = r0; st.y = r1; st.z = r2; st.w = r3;
        *(float4*)(out + (size_t)node * 256 + lane * 4) = st;
    } else {
        float* op = out + (size_t)node * 256 + lane;
        op[0] = r0; op[64] = r1; op[128] = r2; op[192] = r3;
    }
}

extern "C" void kernel_launch(void* const* d_in, const int* in_sizes, int n_in,
                              void* d_out, int out_size, void* d_ws, size_t ws_size,
                              hipStream_t stream) {
    const float* X    = (const float*)d_in[0];
    const int*   ei   = (const int*)d_in[1];
    const float* attr = (const float*)d_in[2];
    const float* w_n1 = (const float*)d_in[3];
    const float* w_e1 = (const float*)d_in[4];
    const float* q1   = (const float*)d_in[5];
    const float* k1   = (const float*)d_in[6];
    const float* aw1  = (const float*)d_in[7];
    const float* ab1  = (const float*)d_in[8];
    const float* ow1  = (const float*)d_in[9];
    const float* ob1  = (const float*)d_in[10];
    const float* w_n2 = (const float*)d_in[11];
    const float* w_e2 = (const float*)d_in[12];
    const float* q2   = (const float*)d_in[13];
    const float* k2   = (const float*)d_in[14];
    const float* aw2  = (const float*)d_in[15];
    const float* ab2  = (const float*)d_in[16];
    const float* ow2  = (const float*)d_in[17];
    const float* ob2  = (const float*)d_in[18];
    float* out = (float*)d_out;

    char* ws = (char*)d_ws;
    float*  xpA    = (float*)(ws + OFF_XPA);
    float*  xpB    = (float*)(ws + OFF_XPB);
    float*  agg    = (float*)(ws + OFF_AGG);
    float*  sa     = (float*)(ws + OFF_SA);
    float*  sb     = (float*)(ws + OFF_SB);
    float*  vecs   = (float*)(ws + OFF_VECS);
    int*    counts = (int*)(ws + OFF_COUNTS);
    int*    cursor = (int*)(ws + OFF_CURSOR);
    int*    offs   = (int*)(ws + OFF_OFFS);
    int2*   recs   = (int2*)(ws + OFF_RECS);
    float4* att    = (float4*)(ws + OFF_ATT);
    float*  gate   = (float*)(ws + OFF_GATE);

    // CSR build (edge_index is layer-invariant)
    hipMemsetAsync(counts, 0, 2 * NN * sizeof(int), stream);  // counts + cursor
    hist_vecs_kernel<<<EE / 256, 256, 0, stream>>>(ei, counts, q1, k1, aw1, w_e1,
                                                   q2, k2, aw2, w_e2, vecs);
    scan_kernel<<<1, 1024, 0, stream>>>(counts, offs, NN);
    scatter_kernel<<<EE / 256, 256, 0, stream>>>(ei, offs, cursor, recs);

    // layer 1
    node_prep_kernel<false><<<NN / 4, 256, 0, stream>>>(X, w_n1, vecs + 0, vecs + 64,
                                                        xpA, sa, sb);
    edge_gate_att_kernel<<<EE / 4, 256, 0, stream>>>(ei, attr, sa, sb, w_e1, vecs + 128,
                                                     ab1, att, gate);
    aggr_kernel<<<NN, 256, 0, stream>>>((const float4*)xpA, recs, offs, att, gate,
                                        (float4*)agg);
    out_kernel<true><<<NN / 4, 256, 0, stream>>>(xpA, agg, ow1, ob1, xpB);

    // layer 2
    node_prep_kernel<true><<<NN / 4, 256, 0, stream>>>(xpB, w_n2, vecs + 144, vecs + 208,
                                                       xpA, sa, sb);
    edge_gate_att_kernel<<<EE / 4, 256, 0, stream>>>(ei, attr, sa, sb, w_e2, vecs + 272,
                                                     ab2, att, gate);
    aggr_kernel<<<NN, 256, 0, stream>>>((const float4*)xpA, recs, offs, att, gate,
                                        (float4*)agg);
    out_kernel<false><<<NN / 4, 256, 0, stream>>>(xpA, agg, ow2, ob2, out);
}

// Round 8
// 331.392 us; speedup vs baseline: 1.1701x; 1.1701x over previous
//
#include <hip/hip_runtime.h>
#include <math.h>

#define NN 10000
#define BB 4
#define EE 160000
#define CC 64
#define CE 16

// ---- workspace layout (bytes), total ~76 MB ----
static constexpr size_t OFF_XPA    = 0;           // float[NN*256]  xp transposed [n][c][b]
static constexpr size_t OFF_XPB    = 10240000;    // float[NN*256]  interlayer act [n][b][c]
static constexpr size_t OFF_SA     = 30720000;    // float[NN*BB]
static constexpr size_t OFF_SB     = 30880000;    // float[NN*BB]
static constexpr size_t OFF_VECS   = 31040000;    // float[288]
static constexpr size_t OFF_COUNTS = 31041280;    // int[NN]
static constexpr size_t OFF_CURSOR = 31081280;    // int[NN]
static constexpr size_t OFF_OFFS   = 31121280;    // int[NN+1] (+pad)
static constexpr size_t OFF_RECS   = 31161344;    // int2[EE]
static constexpr size_t OFF_ATT    = 32441344;    // float4[EE]  (2.56 MB)
static constexpr size_t OFF_GATE   = 35001344;    // float[EE*CC] (40.96 MB)

__device__ __forceinline__ float sigmoidf_(float x) {
    return 1.0f / (1.0f + __expf(-x));
}

// histogram of dst + (block 0) fold q@aw_q, k@aw_k, w_e@aw_e for both layers
__global__ void hist_vecs_kernel(const int* __restrict__ ei, int* __restrict__ counts,
                                 const float* __restrict__ q1, const float* __restrict__ k1,
                                 const float* __restrict__ aw1, const float* __restrict__ we1,
                                 const float* __restrict__ q2, const float* __restrict__ k2,
                                 const float* __restrict__ aw2, const float* __restrict__ we2,
                                 float* __restrict__ vecs) {
    int e = blockIdx.x * blockDim.x + threadIdx.x;
    if (e < EE) atomicAdd(&counts[ei[EE + e]], 1);
    if (blockIdx.x == 0) {
        int t = threadIdx.x;
        if (t < 64) {
            float a = 0.f, b = 0.f, c = 0.f, d = 0.f;
            for (int j = 0; j < 64; ++j) {
                a = fmaf(q1[t * 64 + j], aw1[j], a);
                b = fmaf(k1[t * 64 + j], aw1[64 + j], b);
                c = fmaf(q2[t * 64 + j], aw2[j], c);
                d = fmaf(k2[t * 64 + j], aw2[64 + j], d);
            }
            vecs[t] = a; vecs[64 + t] = b; vecs[144 + t] = c; vecs[208 + t] = d;
        }
        if (t < 16) {
            float a = 0.f, b = 0.f;
            for (int j = 0; j < 64; ++j) {
                a = fmaf(we1[t * 64 + j], aw1[128 + j], a);
                b = fmaf(we2[t * 64 + j], aw2[128 + j], b);
            }
            vecs[128 + t] = a; vecs[272 + t] = b;
        }
    }
}

// single-block exclusive scan via wave shuffles
__global__ void scan_kernel(const int* __restrict__ counts, int* __restrict__ offs, int n) {
    __shared__ int wsum[16];
    __shared__ int carry_sh;
    int t = threadIdx.x;
    int lane = t & 63, wid = t >> 6;
    if (t == 0) carry_sh = 0;
    __syncthreads();
    for (int base = 0; base < n; base += 1024) {
        int i = base + t;
        int v = (i < n) ? counts[i] : 0;
        int x = v;
        #pragma unroll
        for (int d = 1; d < 64; d <<= 1) {
            int y = __shfl_up(x, d, 64);
            if (lane >= d) x += y;
        }
        if (lane == 63) wsum[wid] = x;
        __syncthreads();
        if (wid == 0 && lane < 16) {
            int s = wsum[lane];
            int y2 = s;
            #pragma unroll
            for (int d = 1; d < 16; d <<= 1) {
                int z = __shfl_up(y2, d, 16);
                if (lane >= d) y2 += z;
            }
            wsum[lane] = y2;  // inclusive
        }
        __syncthreads();
        int waveExcl = (wid == 0) ? 0 : wsum[wid - 1];
        int carry = carry_sh;
        if (i < n) offs[i] = carry + waveExcl + x - v;
        int total = wsum[15];
        __syncthreads();
        if (t == 0) carry_sh = carry + total;
        __syncthreads();
    }
    if (threadIdx.x == 0) offs[n] = carry_sh;
}

__global__ void scatter_kernel(const int* __restrict__ ei, const int* __restrict__ offs,
                               int* __restrict__ cursor, int2* __restrict__ recs) {
    int e = blockIdx.x * blockDim.x + threadIdx.x;
    if (e >= EE) return;
    int s = ei[e], d = ei[EE + e];
    int p = atomicAdd(&cursor[d], 1);
    recs[offs[d] + p] = make_int2(s, e);
}

// xp_t = transpose(x @ w_n) ; sa = xp@qa ; sb = xp@ka. One wave per node.
// Input always [n][b][c]; xp_t output [n][c][b].
__global__ __launch_bounds__(256) void node_prep_kernel(
    const float* __restrict__ x,
    const float* __restrict__ w_n, // [CC,CC]
    const float* __restrict__ qa,  // [64]
    const float* __restrict__ ka,  // [64]
    float* __restrict__ xp_t,      // [NN][CC][BB]
    float* __restrict__ sa,        // [NN,BB]
    float* __restrict__ sb) {
    __shared__ float w_sh[64 * 64];     // 16 KB
    __shared__ float x_sh[4 * BB * CC]; // 4 KB
    int t = threadIdx.x;
    for (int i = t; i < 64 * 64; i += 256) w_sh[i] = w_n[i];
    int node0 = blockIdx.x * 4;
    const float4* xg = (const float4*)(x + (size_t)node0 * BB * CC);
    ((float4*)x_sh)[t] = xg[t];
    __syncthreads();
    int wave = t >> 6, lane = t & 63;
    int node = node0 + wave;
    const float* xrow = x_sh + wave * BB * CC;
    float acc0 = 0.f, acc1 = 0.f, acc2 = 0.f, acc3 = 0.f;
    #pragma unroll 8
    for (int ci = 0; ci < 64; ++ci) {
        float w = w_sh[ci * 64 + lane];
        acc0 = fmaf(xrow[ci], w, acc0);
        acc1 = fmaf(xrow[64 + ci], w, acc1);
        acc2 = fmaf(xrow[128 + ci], w, acc2);
        acc3 = fmaf(xrow[192 + ci], w, acc3);
    }
    float4 st; st.x = acc0; st.y = acc1; st.z = acc2; st.w = acc3;
    *(float4*)(xp_t + (size_t)node * 256 + lane * 4) = st;
    float qv = qa[lane], kv = ka[lane];
    float ra0 = acc0 * qv, ra1 = acc1 * qv, ra2 = acc2 * qv, ra3 = acc3 * qv;
    float rb0 = acc0 * kv, rb1 = acc1 * kv, rb2 = acc2 * kv, rb3 = acc3 * kv;
    #pragma unroll
    for (int off = 32; off >= 1; off >>= 1) {
        ra0 += __shfl_xor(ra0, off, 64); ra1 += __shfl_xor(ra1, off, 64);
        ra2 += __shfl_xor(ra2, off, 64); ra3 += __shfl_xor(ra3, off, 64);
        rb0 += __shfl_xor(rb0, off, 64); rb1 += __shfl_xor(rb1, off, 64);
        rb2 += __shfl_xor(rb2, off, 64); rb3 += __shfl_xor(rb3, off, 64);
    }
    if (lane == 0) {
        sa[node * BB + 0] = ra0; sa[node * BB + 1] = ra1;
        sa[node * BB + 2] = ra2; sa[node * BB + 3] = ra3;
        sb[node * BB + 0] = rb0; sb[node * BB + 1] = rb1;
        sb[node * BB + 2] = rb2; sb[node * BB + 3] = rb3;
    }
}

// Tile-GEMM producer: block = 256 edges.
// Phase A (thread-per-edge): load attr row to regs, compute att[e], stage attr
//   tile in LDS (stride 20 to dodge bank conflicts).
// Phase B (wave w = 64 edges, lane = channel): gate[e][c] via LDS-broadcast
//   reads of attr + wec in regs; coalesced 256B stores.
__global__ __launch_bounds__(256) void edge_kernel(
    const int* __restrict__ ei, const float* __restrict__ attr,
    const float* __restrict__ sa, const float* __restrict__ sb,
    const float* __restrict__ w_e,   // [CE,CC]
    const float* __restrict__ weav,  // [16]
    const float* __restrict__ ab,    // [1]
    float4* __restrict__ att, float* __restrict__ gate) {
    __shared__ float attr_sh[256 * 20];  // 20 KB, row stride 20 floats
    int t = threadIdx.x;
    int wid = t >> 6, lane = t & 63;
    int base = blockIdx.x * 256;

    float wec[CE];
    #pragma unroll
    for (int j = 0; j < CE; ++j) wec[j] = w_e[j * CC + lane];

    // ---- Phase A: thread t owns edge base+t ----
    int e = base + t;
    const float4* ap = (const float4*)(attr + (size_t)e * CE);
    float4 a0 = ap[0], a1 = ap[1], a2 = ap[2], a3 = ap[3];
    int s = ei[e], d = ei[EE + e];
    // stage to LDS (b128 stores, 2-way conflict max at stride 20)
    float4* row = (float4*)(attr_sh + t * 20);
    row[0] = a0; row[1] = a1; row[2] = a2; row[3] = a3;
    // att scalar
    float se = ab[0];
    se = fmaf(a0.x, weav[0], se);  se = fmaf(a0.y, weav[1], se);
    se = fmaf(a0.z, weav[2], se);  se = fmaf(a0.w, weav[3], se);
    se = fmaf(a1.x, weav[4], se);  se = fmaf(a1.y, weav[5], se);
    se = fmaf(a1.z, weav[6], se);  se = fmaf(a1.w, weav[7], se);
    se = fmaf(a2.x, weav[8], se);  se = fmaf(a2.y, weav[9], se);
    se = fmaf(a2.z, weav[10], se); se = fmaf(a2.w, weav[11], se);
    se = fmaf(a3.x, weav[12], se); se = fmaf(a3.y, weav[13], se);
    se = fmaf(a3.z, weav[14], se); se = fmaf(a3.w, weav[15], se);
    float4 sas = *(const float4*)(sa + (size_t)s * BB);
    float4 sbn = *(const float4*)(sb + (size_t)d * BB);
    float4 r;
    r.x = sigmoidf_(sas.x + sbn.x + se);
    r.y = sigmoidf_(sas.y + sbn.y + se);
    r.z = sigmoidf_(sas.z + sbn.z + se);
    r.w = sigmoidf_(sas.w + sbn.w + se);
    att[e] = r;
    __syncthreads();

    // ---- Phase B: wave wid covers edges [wid*64, wid*64+64) ----
    int eb = wid * 64;
    #pragma unroll 2
    for (int k = 0; k < 64; ++k) {
        const float4* arow = (const float4*)(attr_sh + (eb + k) * 20);
        float4 b0 = arow[0], b1 = arow[1], b2 = arow[2], b3 = arow[3];  // broadcast
        float g = 0.f;
        g = fmaf(b0.x, wec[0], g);  g = fmaf(b0.y, wec[1], g);
        g = fmaf(b0.z, wec[2], g);  g = fmaf(b0.w, wec[3], g);
        g = fmaf(b1.x, wec[4], g);  g = fmaf(b1.y, wec[5], g);
        g = fmaf(b1.z, wec[6], g);  g = fmaf(b1.w, wec[7], g);
        g = fmaf(b2.x, wec[8], g);  g = fmaf(b2.y, wec[9], g);
        g = fmaf(b2.z, wec[10], g); g = fmaf(b2.w, wec[11], g);
        g = fmaf(b3.x, wec[12], g); g = fmaf(b3.y, wec[13], g);
        g = fmaf(b3.z, wec[14], g); g = fmaf(b3.w, wec[15], g);
        gate[(size_t)(base + eb + k) * CC + lane] = sigmoidf_(g);
    }
}

// Fused segment-max + epilogue GEMM. Block = 1 node.
// Phase 1: 4 waves stripe the in-edge list (pure loads + max), LDS reduce.
// Phase 2: wave b computes output row b: leaky(xp + [xp,agg]@ow + ob).
// Output written [n][b][c] (natural layout).
__global__ __launch_bounds__(256) void aggrout_kernel(
    const float4* __restrict__ xp_t,   // [NN][CC] float4 (b packed)
    const int2* __restrict__ recs,     // [EE] {src, e}
    const int* __restrict__ offs,      // [NN+1]
    const float4* __restrict__ att,    // [EE]
    const float* __restrict__ gate,    // [EE][CC]
    const float* __restrict__ ow,      // [2*CC,CC]
    const float* __restrict__ ob,      // [CC]
    float* __restrict__ out) {         // [NN][BB][CC]
    __shared__ float4 red[4][64];      // 4 KB
    __shared__ float cat_sh[4 * 128];  // 2 KB  [b][k]
    int t = threadIdx.x;
    int wid = t >> 6, lane = t & 63;
    int node = blockIdx.x;

    int o0 = offs[node], o1 = offs[node + 1];
    float m0 = -INFINITY, m1 = -INFINITY, m2 = -INFINITY, m3 = -INFINITY;

    int i = o0 + wid;
    for (; i + 4 < o1; i += 8) {
        int2 rA = recs[i], rB = recs[i + 4];
        float4 xA = xp_t[(size_t)rA.x * 64 + lane];
        float4 xB = xp_t[(size_t)rB.x * 64 + lane];
        float gA = gate[(size_t)rA.y * CC + lane];
        float gB = gate[(size_t)rB.y * CC + lane];
        float4 AA = att[rA.y], AB = att[rB.y];
        m0 = fmaxf(m0, AA.x * xA.x * gA); m1 = fmaxf(m1, AA.y * xA.y * gA);
        m2 = fmaxf(m2, AA.z * xA.z * gA); m3 = fmaxf(m3, AA.w * xA.w * gA);
        m0 = fmaxf(m0, AB.x * xB.x * gB); m1 = fmaxf(m1, AB.y * xB.y * gB);
        m2 = fmaxf(m2, AB.z * xB.z * gB); m3 = fmaxf(m3, AB.w * xB.w * gB);
    }
    for (; i < o1; i += 4) {
        int2 r = recs[i];
        float4 xv = xp_t[(size_t)r.x * 64 + lane];
        float g = gate[(size_t)r.y * CC + lane];
        float4 at = att[r.y];
        m0 = fmaxf(m0, at.x * xv.x * g); m1 = fmaxf(m1, at.y * xv.y * g);
        m2 = fmaxf(m2, at.z * xv.z * g); m3 = fmaxf(m3, at.w * xv.w * g);
    }
    float4 mv; mv.x = m0; mv.y = m1; mv.z = m2; mv.w = m3;
    red[wid][lane] = mv;
    __syncthreads();

    if (wid == 0) {
        float4 a = red[0][lane], b = red[1][lane], c = red[2][lane], d = red[3][lane];
        m0 = fmaxf(fmaxf(a.x, b.x), fmaxf(c.x, d.x));
        m1 = fmaxf(fmaxf(a.y, b.y), fmaxf(c.y, d.y));
        m2 = fmaxf(fmaxf(a.z, b.z), fmaxf(c.z, d.z));
        m3 = fmaxf(fmaxf(a.w, b.w), fmaxf(c.w, d.w));
        m0 = (m0 == -INFINITY) ? 0.f : m0;
        m1 = (m1 == -INFINITY) ? 0.f : m1;
        m2 = (m2 == -INFINITY) ? 0.f : m2;
        m3 = (m3 == -INFINITY) ? 0.f : m3;
        float4 xpn = xp_t[(size_t)node * 64 + lane];
        cat_sh[0 * 128 + lane] = xpn.x; cat_sh[0 * 128 + 64 + lane] = m0;
        cat_sh[1 * 128 + lane] = xpn.y; cat_sh[1 * 128 + 64 + lane] = m1;
        cat_sh[2 * 128 + lane] = xpn.z; cat_sh[2 * 128 + 64 + lane] = m2;
        cat_sh[3 * 128 + lane] = xpn.w; cat_sh[3 * 128 + 64 + lane] = m3;
    }
    __syncthreads();

    // Phase 2: wave wid -> output row b = wid
    const float* crow = cat_sh + wid * 128;
    float acc = 0.f;
    #pragma unroll 8
    for (int k = 0; k < 128; ++k) {
        acc = fmaf(crow[k], ow[k * 64 + lane], acc);
    }
    float rr = crow[lane] + acc + ob[lane];  // crow[lane] == xp[node][b][lane]
    rr = (rr > 0.f) ? rr : 0.01f * rr;
    out[(size_t)node * 256 + wid * 64 + lane] = rr;
}

extern "C" void kernel_launch(void* const* d_in, const int* in_sizes, int n_in,
                              void* d_out, int out_size, void* d_ws, size_t ws_size,
                              hipStream_t stream) {
    const float* X    = (const float*)d_in[0];
    const int*   ei   = (const int*)d_in[1];
    const float* attr = (const float*)d_in[2];
    const float* w_n1 = (const float*)d_in[3];
    const float* w_e1 = (const float*)d_in[4];
    const float* q1   = (const float*)d_in[5];
    const float* k1   = (const float*)d_in[6];
    const float* aw1  = (const float*)d_in[7];
    const float* ab1  = (const float*)d_in[8];
    const float* ow1  = (const float*)d_in[9];
    const float* ob1  = (const float*)d_in[10];
    const float* w_n2 = (const float*)d_in[11];
    const float* w_e2 = (const float*)d_in[12];
    const float* q2   = (const float*)d_in[13];
    const float* k2   = (const float*)d_in[14];
    const float* aw2  = (const float*)d_in[15];
    const float* ab2  = (const float*)d_in[16];
    const float* ow2  = (const float*)d_in[17];
    const float* ob2  = (const float*)d_in[18];
    float* out = (float*)d_out;

    char* ws = (char*)d_ws;
    float*  xpA    = (float*)(ws + OFF_XPA);
    float*  xpB    = (float*)(ws + OFF_XPB);
    float*  sa     = (float*)(ws + OFF_SA);
    float*  sb     = (float*)(ws + OFF_SB);
    float*  vecs   = (float*)(ws + OFF_VECS);
    int*    counts = (int*)(ws + OFF_COUNTS);
    int*    cursor = (int*)(ws + OFF_CURSOR);
    int*    offs   = (int*)(ws + OFF_OFFS);
    int2*   recs   = (int2*)(ws + OFF_RECS);
    float4* att    = (float4*)(ws + OFF_ATT);
    float*  gate   = (float*)(ws + OFF_GATE);

    // CSR build (edge_index is layer-invariant)
    hipMemsetAsync(counts, 0, 2 * NN * sizeof(int), stream);  // counts + cursor
    hist_vecs_kernel<<<EE / 256, 256, 0, stream>>>(ei, counts, q1, k1, aw1, w_e1,
                                                   q2, k2, aw2, w_e2, vecs);
    scan_kernel<<<1, 1024, 0, stream>>>(counts, offs, NN);
    scatter_kernel<<<EE / 256, 256, 0, stream>>>(ei, offs, cursor, recs);

    // layer 1
    node_prep_kernel<<<NN / 4, 256, 0, stream>>>(X, w_n1, vecs + 0, vecs + 64,
                                                 xpA, sa, sb);
    edge_kernel<<<EE / 256, 256, 0, stream>>>(ei, attr, sa, sb, w_e1, vecs + 128,
                                              ab1, att, gate);
    aggrout_kernel<<<NN, 256, 0, stream>>>((const float4*)xpA, recs, offs, att, gate,
                                           ow1, ob1, xpB);

    // layer 2
    node_prep_kernel<<<NN / 4, 256, 0, stream>>>(xpB, w_n2, vecs + 144, vecs + 208,
                                                 xpA, sa, sb);
    edge_kernel<<<EE / 256, 256, 0, stream>>>(ei, attr, sa, sb, w_e2, vecs + 272,
                                              ab2, att, gate);
    aggrout_kernel<<<NN, 256, 0, stream>>>((const float4*)xpA, recs, offs, att, gate,
                                           ow2, ob2, out);
}